// Round 8
// baseline (234.487 us; speedup 1.0000x reference)
//
#include <hip/hip_runtime.h>
#include <hip/hip_fp16.h>
#include <math.h>

#define NN 50000
#define NE 3200000

#define NT    128        // dst tiles of 392 nodes: 128*392 = 50176 >= NN
#define TSZ   392
#define CAP   26624      // bucket capacity per tile (mean 25000, ~10 sigma margin)
#define SCB   1250       // scatter blocks -> 4.9 blocks/CU
#define EPB   2560       // edges per scatter block
#define EPT   10         // edges per thread (EPB/256)
#define NSL   12         // agg slices per tile -> 128*12 = 1536 = 6 blocks/CU

static constexpr float ACC_SCALE   = 0.005f;
static constexpr float MAX_VEL     = 0.02f;
static constexpr float NOISE_SCALE = 0.004f;
static constexpr float RADIUS      = 0.05f;

// d_out layout (float32): new_x[N*10], keep[N], scalars[7]
#define OUT_KEEP   500000
#define OUT_SCAL   550000
// scalars: 0,1 velocity_bonus; 2 border_cost; 3 food_reward; 4 dead_cost;
//          5 visible_food; 6 mean_food_dist

// ws layout (float units):
#define WS_SREC  0          // float4[50176*3] (48B/node)   -> 602112
#define WS_GCUR  602112     // int[NT*16] padded            -> 604160
#define WS_BK    604160     // uint[NT*CAP = 3407872]       -> 4012032
#define WS_PACC  4012032    // float4[NSL*50176] = 2408448  -> 6420480
#define WS_PDEG  6420480    // int[NSL*50176 = 602112]      -> 7022592 (~28.1 MB; ws >= 33.7 MB proven R5)

// ---------------------------------------------------------------------------
// Kernel 1: per-node precompute.  48-byte src-record:
//   [px, py, cell, pad][s2[0..7] fp16][s2[8..15] fp16]
// ---------------------------------------------------------------------------
__global__ __launch_bounds__(256) void k1_prep(
    const float* __restrict__ x,
    const float* __restrict__ W_edge,   // (4,16)
    const float* __restrict__ W_src,    // (10,16)
    const float* __restrict__ b1,       // (16,)
    float4* __restrict__ srec,
    int* __restrict__ gcur,
    float* __restrict__ out_scalars)
{
    int n = blockIdx.x * 256 + threadIdx.x;
    if (blockIdx.x == 0) {
        if (threadIdx.x < 7) out_scalars[threadIdx.x] = 0.0f;
        for (int i = threadIdx.x; i < NT * 16; i += 256)
            gcur[i] = (i & 15) ? 0 : (i >> 4) * CAP;
    }
    if (n >= NN) return;

    float xr[10];
#pragma unroll
    for (int c = 0; c < 10; ++c) xr[c] = x[n * 10 + c];
    float cell = xr[4];

    float v[16];
#pragma unroll
    for (int j = 0; j < 16; ++j) {
        float a = fmaf(cell, W_edge[48 + j], b1[j]);
#pragma unroll
        for (int c = 0; c < 10; ++c) a = fmaf(xr[c], W_src[c * 16 + j], a);
        v[j] = a;
    }

    float4 r1, r2;
    r1.x = __builtin_bit_cast(float, __floats2half2_rn(v[0],  v[1]));
    r1.y = __builtin_bit_cast(float, __floats2half2_rn(v[2],  v[3]));
    r1.z = __builtin_bit_cast(float, __floats2half2_rn(v[4],  v[5]));
    r1.w = __builtin_bit_cast(float, __floats2half2_rn(v[6],  v[7]));
    r2.x = __builtin_bit_cast(float, __floats2half2_rn(v[8],  v[9]));
    r2.y = __builtin_bit_cast(float, __floats2half2_rn(v[10], v[11]));
    r2.z = __builtin_bit_cast(float, __floats2half2_rn(v[12], v[13]));
    r2.w = __builtin_bit_cast(float, __floats2half2_rn(v[14], v[15]));

    srec[(size_t)n * 3 + 0] = make_float4(xr[0], xr[1], cell, 0.0f);
    srec[(size_t)n * 3 + 1] = r1;
    srec[(size_t)n * 3 + 2] = r2;
}

// ---------------------------------------------------------------------------
// Kernel 2: per-block LDS counting sort of a 2560-edge chunk, one coalesced
// nontemporal flush.  Entry = src(16b) | dst_local(9b)<<16 | bin(7b)<<25.
// ---------------------------------------------------------------------------
__global__ __launch_bounds__(256) void k_scatter(
    const int* __restrict__ src,
    const int* __restrict__ dst,
    int* __restrict__ gcur,
    unsigned* __restrict__ bucket)
{
    __shared__ unsigned stage[EPB];                          // 10.2 KB
    __shared__ int hist[NT], binstart[NT], lcur[NT], gbase[NT];
    __shared__ int scanbuf[128];

    int tid = threadIdx.x;
    for (int i = tid; i < NT; i += 256) { hist[i] = 0; lcur[i] = 0; }
    __syncthreads();

    int e0 = blockIdx.x * EPB;

    // phase 1: histogram; dst kept in registers
    int d[EPT];
#pragma unroll
    for (int j = 0; j < EPT; ++j) d[j] = dst[e0 + j * 256 + tid];
#pragma unroll
    for (int j = 0; j < EPT; ++j) atomicAdd(&hist[d[j] / TSZ], 1);
    __syncthreads();

    // phase 2: exclusive scan over 128 bins
    if (tid < 128) scanbuf[tid] = hist[tid];
    __syncthreads();
    for (int off = 1; off < 128; off <<= 1) {
        int v = 0;
        if (tid < 128 && tid >= off) v = scanbuf[tid - off];
        __syncthreads();
        if (tid < 128) scanbuf[tid] += v;
        __syncthreads();
    }
    if (tid < 128) {
        int tt = (tid + blockIdx.x) & 127;    // rotated atomic order
        int bs = scanbuf[tt] - hist[tt];
        binstart[tt] = bs;
        gbase[tt] = atomicAdd(&gcur[tt * 16], hist[tt]) - bs;
    }
    __syncthreads();

    // phase 3: placement into sorted LDS stage (bin id packed in top bits)
    int sreg[EPT];
#pragma unroll
    for (int j = 0; j < EPT; ++j) sreg[j] = src[e0 + j * 256 + tid];
#pragma unroll
    for (int j = 0; j < EPT; ++j) {
        int t  = d[j] / TSZ;
        int dl = d[j] - t * TSZ;
        int pos = binstart[t] + atomicAdd(&lcur[t], 1);
        stage[pos] = (unsigned)sreg[j] | ((unsigned)dl << 16)
                   | ((unsigned)t << 25);
    }
    __syncthreads();

    // phase 4: coalesced nontemporal flush
#pragma unroll
    for (int j = 0; j < EPT; ++j) {
        int i = j * 256 + tid;
        unsigned e = stage[i];
        int b = e >> 25;
        int g = gbase[b] + i;
        if (g < (b + 1) * CAP) __builtin_nontemporal_store(e, &bucket[g]);
    }
}

// ---------------------------------------------------------------------------
// Kernel 3: aggregation.  Explicit 4-wide gather batching; grid = 6 blocks/CU.
// ---------------------------------------------------------------------------
__global__ __launch_bounds__(256, 2) void k_agg(
    const float* __restrict__ W_edge,   // (4,16)
    const float* __restrict__ W_out,    // (16,4)
    const float4* __restrict__ srec,
    const int* __restrict__ gcur,
    const unsigned* __restrict__ bucket,
    float4* __restrict__ pacc,
    int* __restrict__ pdeg,
    float* __restrict__ out_scalars)
{
    __shared__ float sAcc[TSZ][5];      // stride 5: coprime with 32 banks
    __shared__ int   sDeg[TSZ];
    __shared__ float sPX[TSZ], sPY[TSZ], sCL[TSZ];
    __shared__ float sRed[4][2];

    int t   = blockIdx.x / NSL;
    int sl  = blockIdx.x - t * NSL;
    int tid = threadIdx.x;

    for (int j = tid; j < TSZ; j += 256) {
        int g = t * TSZ + j;
        float4 ni = (g < NN) ? srec[(size_t)g * 3]
                             : make_float4(9e9f, 9e9f, -1.f, 0.f);
        sPX[j] = ni.x; sPY[j] = ni.y; sCL[j] = ni.z;
        sAcc[j][0] = 0.f; sAcc[j][1] = 0.f; sAcc[j][2] = 0.f; sAcc[j][3] = 0.f;
        sDeg[j] = 0;
    }

    // wave-uniform weights -> SGPRs
    float w0[16], w1[16], w2[16], woa[16], wob[16], woc[16], wod[16];
#pragma unroll
    for (int k = 0; k < 16; ++k) {
        w0[k] = W_edge[k];
        w1[k] = W_edge[16 + k];
        w2[k] = W_edge[32 + k];
        woa[k] = W_out[k * 4 + 0];
        wob[k] = W_out[k * 4 + 1];
        woc[k] = W_out[k * 4 + 2];
        wod[k] = W_out[k * 4 + 3];
    }
    __syncthreads();

    int cnt = gcur[t * 16] - t * CAP;
    if (cnt > CAP) cnt = CAP;
    int per = (cnt + NSL - 1) / NSL;
    int i0 = sl * per;
    int i1 = min(i0 + per, cnt);

    const unsigned* bk = bucket + (size_t)t * CAP;
    float vis = 0.f, fd = 0.f;

    auto PROC = [&](unsigned e, float4 A, float4 B, float4 C) {
        int dl = (e >> 16) & 0x1FF;
        float dx = A.x - sPX[dl];
        float dy = A.y - sPY[dl];
        float dist = sqrtf(fmaf(dx, dx, fmaf(dy, dy, 1e-12f)));

        bool food0 = (A.z == 0.0f);
        vis += food0 ? 1.f : 0.f;
        fd  += food0 ? dist : 0.f;

        bool consume = (dist < RADIUS) && (A.z == 1.0f) && (sCL[dl] == 0.0f);
        atomicAdd(&sDeg[dl], consume ? 65537 : 1);

        float sv[16];
        float2 f;
        f = __half22float2(__builtin_bit_cast(__half2, B.x)); sv[0]=f.x;  sv[1]=f.y;
        f = __half22float2(__builtin_bit_cast(__half2, B.y)); sv[2]=f.x;  sv[3]=f.y;
        f = __half22float2(__builtin_bit_cast(__half2, B.z)); sv[4]=f.x;  sv[5]=f.y;
        f = __half22float2(__builtin_bit_cast(__half2, B.w)); sv[6]=f.x;  sv[7]=f.y;
        f = __half22float2(__builtin_bit_cast(__half2, C.x)); sv[8]=f.x;  sv[9]=f.y;
        f = __half22float2(__builtin_bit_cast(__half2, C.y)); sv[10]=f.x; sv[11]=f.y;
        f = __half22float2(__builtin_bit_cast(__half2, C.z)); sv[12]=f.x; sv[13]=f.y;
        f = __half22float2(__builtin_bit_cast(__half2, C.w)); sv[14]=f.x; sv[15]=f.y;

        float v0 = 0.f, v1 = 0.f, v2 = 0.f, v3 = 0.f;
#pragma unroll
        for (int k = 0; k < 16; ++k) {
            float m = fmaf(dist, w0[k], fmaf(dx, w1[k], fmaf(dy, w2[k], sv[k])));
            m = fmaxf(m, 0.0f);
            v0 = fmaf(m, woa[k], v0);
            v1 = fmaf(m, wob[k], v1);
            v2 = fmaf(m, woc[k], v2);
            v3 = fmaf(m, wod[k], v3);
        }
        atomicAdd(&sAcc[dl][0], v0);
        atomicAdd(&sAcc[dl][1], v1);
        atomicAdd(&sAcc[dl][2], v2);
        atomicAdd(&sAcc[dl][3], v3);
    };

#pragma unroll 1
    for (int base = i0 + tid; base < i1; base += 1024) {
        int iend = i1 - 1;
        int j1 = min(base + 256, iend);
        int j2 = min(base + 512, iend);
        int j3 = min(base + 768, iend);

        // 4 bucket loads issued together
        unsigned e0 = __builtin_nontemporal_load(&bk[base]);
        unsigned e1 = __builtin_nontemporal_load(&bk[j1]);
        unsigned e2 = __builtin_nontemporal_load(&bk[j2]);
        unsigned e3 = __builtin_nontemporal_load(&bk[j3]);

        // 12 srec gathers issued back-to-back
        const float4* p0 = srec + (size_t)(e0 & 0xFFFF) * 3;
        const float4* p1 = srec + (size_t)(e1 & 0xFFFF) * 3;
        const float4* p2 = srec + (size_t)(e2 & 0xFFFF) * 3;
        const float4* p3 = srec + (size_t)(e3 & 0xFFFF) * 3;
        float4 A0 = p0[0], B0 = p0[1], C0 = p0[2];
        float4 A1 = p1[0], B1 = p1[1], C1 = p1[2];
        float4 A2 = p2[0], B2 = p2[1], C2 = p2[2];
        float4 A3 = p3[0], B3 = p3[1], C3 = p3[2];

        PROC(e0, A0, B0, C0);
        if (base + 256 < i1) PROC(e1, A1, B1, C1);
        if (base + 512 < i1) PROC(e2, A2, B2, C2);
        if (base + 768 < i1) PROC(e3, A3, B3, C3);
    }
    __syncthreads();

    // write partials (coalesced)
    for (int j = tid; j < TSZ; j += 256) {
        int o = sl * (NT * TSZ) + t * TSZ + j;
        pacc[o] = make_float4(sAcc[j][0], sAcc[j][1], sAcc[j][2], sAcc[j][3]);
        pdeg[o] = sDeg[j];
    }

    // block-reduce vis/fd
#pragma unroll
    for (int off = 32; off > 0; off >>= 1) {
        vis += __shfl_down(vis, off);
        fd  += __shfl_down(fd,  off);
    }
    int lane = tid & 63, wv = tid >> 6;
    if (lane == 0) { sRed[wv][0] = vis; sRed[wv][1] = fd; }
    __syncthreads();
    if (tid == 0) {
        float a = 0.f, b = 0.f;
#pragma unroll
        for (int wq = 0; wq < 4; ++wq) { a += sRed[wq][0]; b += sRed[wq][1]; }
        atomicAdd(&out_scalars[5], a);
        atomicAdd(&out_scalars[6], b);
    }
}

// ---------------------------------------------------------------------------
// Kernel 4: merge partials + node finalize.  392 blocks, 2 threads per node.
// ---------------------------------------------------------------------------
__global__ __launch_bounds__(256) void k_final(
    const float* __restrict__ x,
    const float* __restrict__ noise,
    const float* __restrict__ b2,       // (4,)
    const float4* __restrict__ pacc,
    const int* __restrict__ pdeg,
    float* __restrict__ out,
    float* __restrict__ out_scalars)
{
    __shared__ float sRed[4][5];
    int tid  = threadIdx.x;
    int n    = blockIdx.x * 128 + (tid >> 1);
    int half = tid & 1;

    float a0 = 0.f, a1 = 0.f, a2 = 0.f, a3 = 0.f;
    int dp = 0;
    if (n < NN) {
#pragma unroll
        for (int k = 0; k < NSL / 2; ++k) {
            int o = (2 * k + half) * (NT * TSZ) + n;
            float4 q = pacc[o];
            a0 += q.x; a1 += q.y; a2 += q.z; a3 += q.w;
            dp += pdeg[o];
        }
    }
    a0 += __shfl_xor(a0, 1);
    a1 += __shfl_xor(a1, 1);
    a2 += __shfl_xor(a2, 1);
    a3 += __shfl_xor(a3, 1);
    dp += __shfl_xor(dp, 1);

    float avx = 0.f, avy = 0.f, bc = 0.f, deadf = 0.f, consf = 0.f;
    if (n < NN && half == 0) {
        float cell = x[n * 10 + 4];
        float cm = (cell == 1.0f) ? 1.0f : 0.0f;
        float h0 = tanhf(a0 + b2[0]) * cm;
        float h1 = tanhf(a1 + b2[1]) * cm;
        float h2 = tanhf(a2 + b2[2]) * cm;
        float h3 = tanhf(a3 + b2[3]) * cm;

        float px = x[n * 10 + 0], py = x[n * 10 + 1];
        float vx = x[n * 10 + 2], vy = x[n * 10 + 3];

        float nvx = fminf(fmaxf(fmaf(h0, ACC_SCALE, vx), -MAX_VEL), MAX_VEL);
        float nvy = fminf(fmaxf(fmaf(h1, ACC_SCALE, vy), -MAX_VEL), MAX_VEL);
        float npx = px + nvx;
        float npy = py + nvy;

        float vnx = nvx + (noise[n * 2 + 0] * 2.0f - 1.0f) * NOISE_SCALE * cm;
        float vny = nvy + (noise[n * 2 + 1] * 2.0f - 1.0f) * NOISE_SCALE * cm;

        float* row = out + (size_t)n * 10;
        row[0] = npx;  row[1] = npy;
        row[2] = vnx;  row[3] = vny;
        row[4] = cell; row[5] = h2;  row[6] = h3;
        row[7] = x[n * 10 + 7];
        row[8] = x[n * 10 + 8];
        row[9] = x[n * 10 + 9];

        float apx = fabsf(npx), apy = fabsf(npy);
        if (apx > 1.0f) bc += logf(apx + 1e-6f);
        if (apy > 1.0f) bc += logf(apy + 1e-6f);

        int deg  = dp & 0xFFFF;
        int cdeg = dp >> 16;
        bool dead = (cell == 1.0f) && (deg < 3);
        bool cons = (cell == 0.0f) && (cdeg >= 3);
        out[OUT_KEEP + n] = (dead || cons) ? 0.0f : 1.0f;
        deadf = dead ? 1.0f : 0.0f;
        consf = cons ? 1.0f : 0.0f;
        avx = fabsf(nvx) * (1.0f / NN);
        avy = fabsf(nvy) * (1.0f / NN);
    }

    float r[5] = { avx, avy, bc, consf, deadf };
#pragma unroll
    for (int q = 0; q < 5; ++q) {
#pragma unroll
        for (int off = 32; off > 0; off >>= 1)
            r[q] += __shfl_down(r[q], off);
    }
    int lane = tid & 63, wv = tid >> 6;
    if (lane == 0) {
#pragma unroll
        for (int q = 0; q < 5; ++q) sRed[wv][q] = r[q];
    }
    __syncthreads();
    if (tid == 0) {
#pragma unroll
        for (int q = 0; q < 5; ++q) {
            float acc = sRed[0][q] + sRed[1][q] + sRed[2][q] + sRed[3][q];
            atomicAdd(&out_scalars[q], acc);
        }
    }
}

extern "C" void kernel_launch(void* const* d_in, const int* in_sizes, int n_in,
                              void* d_out, int out_size, void* d_ws, size_t ws_size,
                              hipStream_t stream) {
    const float* x      = (const float*)d_in[0];
    const int*   src    = (const int*)  d_in[1];
    const int*   dst    = (const int*)  d_in[2];
    const float* noise  = (const float*)d_in[3];
    const float* W_edge = (const float*)d_in[4];
    const float* W_src  = (const float*)d_in[5];
    const float* b1     = (const float*)d_in[6];
    const float* W_out  = (const float*)d_in[7];
    const float* b2     = (const float*)d_in[8];

    float* ws = (float*)d_ws;
    float4*   srec   = (float4*)(ws + WS_SREC);
    int*      gcur   = (int*)(ws + WS_GCUR);
    unsigned* bucket = (unsigned*)(ws + WS_BK);
    float4*   pacc   = (float4*)(ws + WS_PACC);
    int*      pdeg   = (int*)(ws + WS_PDEG);

    float* out         = (float*)d_out;
    float* out_scalars = out + OUT_SCAL;

    k1_prep<<<196, 256, 0, stream>>>(
        x, W_edge, W_src, b1, srec, gcur, out_scalars);

    k_scatter<<<SCB, 256, 0, stream>>>(src, dst, gcur, bucket);

    k_agg<<<NT * NSL, 256, 0, stream>>>(
        W_edge, W_out, srec, gcur, bucket, pacc, pdeg, out_scalars);

    k_final<<<392, 256, 0, stream>>>(
        x, noise, b2, pacc, pdeg, out, out_scalars);
}

// Round 10
// 216.682 us; speedup vs baseline: 1.0822x; 1.0822x over previous
//
#include <hip/hip_runtime.h>
#include <hip/hip_fp16.h>
#include <math.h>

#define NN 50000
#define NE 3200000

#define NT    128        // dst tiles of 392 nodes: 128*392 = 50176 >= NN
#define TSZ   392
#define CAP   26624      // bucket capacity per tile (mean 25000, ~10 sigma margin)
#define SCB   625        // scatter blocks (R7 best-total config)
#define EPB   5120       // edges per scatter block
#define EPT   20         // edges per thread (EPB/256)
#define NSL   6          // agg slices per tile -> 768 blocks = 3/CU

static constexpr float ACC_SCALE   = 0.005f;
static constexpr float MAX_VEL     = 0.02f;
static constexpr float NOISE_SCALE = 0.004f;
static constexpr float RADIUS      = 0.05f;

// d_out layout (float32): new_x[N*10], keep[N], scalars[7]
#define OUT_KEEP   500000
#define OUT_SCAL   550000
// scalars: 0,1 velocity_bonus; 2 border_cost; 3 food_reward; 4 dead_cost;
//          5 visible_food; 6 mean_food_dist

// ws layout (float units):
#define WS_SREC  0          // float4[50176*4] 64B-aligned records -> 802816
#define WS_GCUR  802816     // int[NT*16] padded                  -> 804864
#define WS_BK    804864     // uint[NT*CAP = 3407872]             -> 4212736
#define WS_PACC  4212736    // float4[NSL*50176] = 1204224        -> 5416960
#define WS_PDEG  5416960    // int[NSL*50176 = 301056]            -> 5718016 (~22.9 MB)

// ---------------------------------------------------------------------------
// Kernel 1: per-node precompute.  64-byte ALIGNED src-record (1 cacheline):
//   [px, py, cell, pad][s2[0..7] fp16][s2[8..15] fp16][pad]
// All 3 divergent gathers in k_agg hit the same 64B line, never 2.
// ---------------------------------------------------------------------------
__global__ __launch_bounds__(256) void k1_prep(
    const float* __restrict__ x,
    const float* __restrict__ W_edge,   // (4,16)
    const float* __restrict__ W_src,    // (10,16)
    const float* __restrict__ b1,       // (16,)
    float4* __restrict__ srec,
    int* __restrict__ gcur,
    float* __restrict__ out_scalars)
{
    int n = blockIdx.x * 256 + threadIdx.x;
    if (blockIdx.x == 0) {
        if (threadIdx.x < 7) out_scalars[threadIdx.x] = 0.0f;
        for (int i = threadIdx.x; i < NT * 16; i += 256)
            gcur[i] = (i & 15) ? 0 : (i >> 4) * CAP;
    }
    if (n >= NN) return;

    float xr[10];
#pragma unroll
    for (int c = 0; c < 10; ++c) xr[c] = x[n * 10 + c];
    float cell = xr[4];

    float v[16];
#pragma unroll
    for (int j = 0; j < 16; ++j) {
        float a = fmaf(cell, W_edge[48 + j], b1[j]);
#pragma unroll
        for (int c = 0; c < 10; ++c) a = fmaf(xr[c], W_src[c * 16 + j], a);
        v[j] = a;
    }

    float4 r1, r2;
    r1.x = __builtin_bit_cast(float, __floats2half2_rn(v[0],  v[1]));
    r1.y = __builtin_bit_cast(float, __floats2half2_rn(v[2],  v[3]));
    r1.z = __builtin_bit_cast(float, __floats2half2_rn(v[4],  v[5]));
    r1.w = __builtin_bit_cast(float, __floats2half2_rn(v[6],  v[7]));
    r2.x = __builtin_bit_cast(float, __floats2half2_rn(v[8],  v[9]));
    r2.y = __builtin_bit_cast(float, __floats2half2_rn(v[10], v[11]));
    r2.z = __builtin_bit_cast(float, __floats2half2_rn(v[12], v[13]));
    r2.w = __builtin_bit_cast(float, __floats2half2_rn(v[14], v[15]));

    srec[(size_t)n * 4 + 0] = make_float4(xr[0], xr[1], cell, 0.0f);
    srec[(size_t)n * 4 + 1] = r1;
    srec[(size_t)n * 4 + 2] = r2;
    // slot 3 left as pad (never read)
}

// ---------------------------------------------------------------------------
// Kernel 2: per-block LDS counting sort of a 5120-edge chunk, one coalesced
// nontemporal flush.  Entry = src(16b) | dst_local(9b)<<16 | bin(7b)<<25.
// ---------------------------------------------------------------------------
__global__ __launch_bounds__(256) void k_scatter(
    const int* __restrict__ src,
    const int* __restrict__ dst,
    int* __restrict__ gcur,
    unsigned* __restrict__ bucket)
{
    __shared__ unsigned stage[EPB];                          // 20.5 KB
    __shared__ int hist[NT], binstart[NT], lcur[NT], gbase[NT];
    __shared__ int scanbuf[128];

    int tid = threadIdx.x;
    for (int i = tid; i < NT; i += 256) { hist[i] = 0; lcur[i] = 0; }
    __syncthreads();

    int e0 = blockIdx.x * EPB;

    // phase 1: histogram; dst kept in registers
    int d[EPT];
#pragma unroll
    for (int j = 0; j < EPT; ++j) d[j] = dst[e0 + j * 256 + tid];
#pragma unroll
    for (int j = 0; j < EPT; ++j) atomicAdd(&hist[d[j] / TSZ], 1);
    __syncthreads();

    // phase 2: exclusive scan over 128 bins
    if (tid < 128) scanbuf[tid] = hist[tid];
    __syncthreads();
    for (int off = 1; off < 128; off <<= 1) {
        int v = 0;
        if (tid < 128 && tid >= off) v = scanbuf[tid - off];
        __syncthreads();
        if (tid < 128) scanbuf[tid] += v;
        __syncthreads();
    }
    if (tid < 128) {
        int tt = (tid + blockIdx.x) & 127;    // rotated atomic order
        int bs = scanbuf[tt] - hist[tt];
        binstart[tt] = bs;
        gbase[tt] = atomicAdd(&gcur[tt * 16], hist[tt]) - bs;
    }
    __syncthreads();

    // phase 3: placement into sorted LDS stage (bin id packed in top bits)
    int sreg[EPT];
#pragma unroll
    for (int j = 0; j < EPT; ++j) sreg[j] = src[e0 + j * 256 + tid];
#pragma unroll
    for (int j = 0; j < EPT; ++j) {
        int t  = d[j] / TSZ;
        int dl = d[j] - t * TSZ;
        int pos = binstart[t] + atomicAdd(&lcur[t], 1);
        stage[pos] = (unsigned)sreg[j] | ((unsigned)dl << 16)
                   | ((unsigned)t << 25);
    }
    __syncthreads();

    // phase 4: coalesced nontemporal flush
#pragma unroll
    for (int j = 0; j < EPT; ++j) {
        int i = j * 256 + tid;
        unsigned e = stage[i];
        int b = e >> 25;
        int g = gbase[b] + i;
        if (g < (b + 1) * CAP) __builtin_nontemporal_store(e, &bucket[g]);
    }
}

// ---------------------------------------------------------------------------
// Kernel 3: aggregation.  4-wide gather batching; each edge's 3 divergent
// loads hit ONE 64B line (aligned record).  Single b128 LDS read for dst.
// ---------------------------------------------------------------------------
__global__ __launch_bounds__(256, 2) void k_agg(
    const float* __restrict__ W_edge,   // (4,16)
    const float* __restrict__ W_out,    // (16,4)
    const float4* __restrict__ srec,
    const int* __restrict__ gcur,
    const unsigned* __restrict__ bucket,
    float4* __restrict__ pacc,
    int* __restrict__ pdeg,
    float* __restrict__ out_scalars)
{
    __shared__ float  sAcc[TSZ][5];     // stride 5: coprime with 32 banks
    __shared__ int    sDeg[TSZ];
    __shared__ float4 sNI[TSZ];         // one b128 read per edge
    __shared__ float  sRed[4][2];

    int t   = blockIdx.x / NSL;
    int sl  = blockIdx.x - t * NSL;
    int tid = threadIdx.x;

    for (int j = tid; j < TSZ; j += 256) {
        int g = t * TSZ + j;
        sNI[j] = (g < NN) ? srec[(size_t)g * 4]
                          : make_float4(9e9f, 9e9f, -1.f, 0.f);
        sAcc[j][0] = 0.f; sAcc[j][1] = 0.f; sAcc[j][2] = 0.f; sAcc[j][3] = 0.f;
        sDeg[j] = 0;
    }

    // wave-uniform weights -> SGPRs
    float w0[16], w1[16], w2[16], woa[16], wob[16], woc[16], wod[16];
#pragma unroll
    for (int k = 0; k < 16; ++k) {
        w0[k] = W_edge[k];
        w1[k] = W_edge[16 + k];
        w2[k] = W_edge[32 + k];
        woa[k] = W_out[k * 4 + 0];
        wob[k] = W_out[k * 4 + 1];
        woc[k] = W_out[k * 4 + 2];
        wod[k] = W_out[k * 4 + 3];
    }
    __syncthreads();

    int cnt = gcur[t * 16] - t * CAP;
    if (cnt > CAP) cnt = CAP;
    int per = (cnt + NSL - 1) / NSL;
    int i0 = sl * per;
    int i1 = min(i0 + per, cnt);

    const unsigned* bk = bucket + (size_t)t * CAP;
    float vis = 0.f, fd = 0.f;

    auto PROC = [&](unsigned e, float4 A, float4 B, float4 C) {
        int dl = (e >> 16) & 0x1FF;
        float4 ni = sNI[dl];
        float dx = A.x - ni.x;
        float dy = A.y - ni.y;
        float dist = sqrtf(fmaf(dx, dx, fmaf(dy, dy, 1e-12f)));

        bool food0 = (A.z == 0.0f);
        vis += food0 ? 1.f : 0.f;
        fd  += food0 ? dist : 0.f;

        bool consume = (dist < RADIUS) && (A.z == 1.0f) && (ni.z == 0.0f);
        atomicAdd(&sDeg[dl], consume ? 65537 : 1);

        float sv[16];
        float2 f;
        f = __half22float2(__builtin_bit_cast(__half2, B.x)); sv[0]=f.x;  sv[1]=f.y;
        f = __half22float2(__builtin_bit_cast(__half2, B.y)); sv[2]=f.x;  sv[3]=f.y;
        f = __half22float2(__builtin_bit_cast(__half2, B.z)); sv[4]=f.x;  sv[5]=f.y;
        f = __half22float2(__builtin_bit_cast(__half2, B.w)); sv[6]=f.x;  sv[7]=f.y;
        f = __half22float2(__builtin_bit_cast(__half2, C.x)); sv[8]=f.x;  sv[9]=f.y;
        f = __half22float2(__builtin_bit_cast(__half2, C.y)); sv[10]=f.x; sv[11]=f.y;
        f = __half22float2(__builtin_bit_cast(__half2, C.z)); sv[12]=f.x; sv[13]=f.y;
        f = __half22float2(__builtin_bit_cast(__half2, C.w)); sv[14]=f.x; sv[15]=f.y;

        float v0 = 0.f, v1 = 0.f, v2 = 0.f, v3 = 0.f;
#pragma unroll
        for (int k = 0; k < 16; ++k) {
            float m = fmaf(dist, w0[k], fmaf(dx, w1[k], fmaf(dy, w2[k], sv[k])));
            m = fmaxf(m, 0.0f);
            v0 = fmaf(m, woa[k], v0);
            v1 = fmaf(m, wob[k], v1);
            v2 = fmaf(m, woc[k], v2);
            v3 = fmaf(m, wod[k], v3);
        }
        atomicAdd(&sAcc[dl][0], v0);
        atomicAdd(&sAcc[dl][1], v1);
        atomicAdd(&sAcc[dl][2], v2);
        atomicAdd(&sAcc[dl][3], v3);
    };

#pragma unroll 1
    for (int base = i0 + tid; base < i1; base += 1024) {
        int iend = i1 - 1;
        int j1 = min(base + 256, iend);
        int j2 = min(base + 512, iend);
        int j3 = min(base + 768, iend);

        // 4 bucket loads issued together (coalesced within wave)
        unsigned e0 = __builtin_nontemporal_load(&bk[base]);
        unsigned e1 = __builtin_nontemporal_load(&bk[j1]);
        unsigned e2 = __builtin_nontemporal_load(&bk[j2]);
        unsigned e3 = __builtin_nontemporal_load(&bk[j3]);

        // 12 srec gathers; each edge's 3 loads hit one aligned 64B line
        const float4* p0 = srec + (size_t)(e0 & 0xFFFF) * 4;
        const float4* p1 = srec + (size_t)(e1 & 0xFFFF) * 4;
        const float4* p2 = srec + (size_t)(e2 & 0xFFFF) * 4;
        const float4* p3 = srec + (size_t)(e3 & 0xFFFF) * 4;
        float4 A0 = p0[0], B0 = p0[1], C0 = p0[2];
        float4 A1 = p1[0], B1 = p1[1], C1 = p1[2];
        float4 A2 = p2[0], B2 = p2[1], C2 = p2[2];
        float4 A3 = p3[0], B3 = p3[1], C3 = p3[2];

        PROC(e0, A0, B0, C0);
        if (base + 256 < i1) PROC(e1, A1, B1, C1);
        if (base + 512 < i1) PROC(e2, A2, B2, C2);
        if (base + 768 < i1) PROC(e3, A3, B3, C3);
    }
    __syncthreads();

    // write partials (coalesced)
    for (int j = tid; j < TSZ; j += 256) {
        int o = sl * (NT * TSZ) + t * TSZ + j;
        pacc[o] = make_float4(sAcc[j][0], sAcc[j][1], sAcc[j][2], sAcc[j][3]);
        pdeg[o] = sDeg[j];
    }

    // block-reduce vis/fd
#pragma unroll
    for (int off = 32; off > 0; off >>= 1) {
        vis += __shfl_down(vis, off);
        fd  += __shfl_down(fd,  off);
    }
    int lane = tid & 63, wv = tid >> 6;
    if (lane == 0) { sRed[wv][0] = vis; sRed[wv][1] = fd; }
    __syncthreads();
    if (tid == 0) {
        float a = 0.f, b = 0.f;
#pragma unroll
        for (int wq = 0; wq < 4; ++wq) { a += sRed[wq][0]; b += sRed[wq][1]; }
        atomicAdd(&out_scalars[5], a);
        atomicAdd(&out_scalars[6], b);
    }
}

// ---------------------------------------------------------------------------
// Kernel 4: merge partials + node finalize.  392 blocks, 2 threads per node.
// ---------------------------------------------------------------------------
__global__ __launch_bounds__(256) void k_final(
    const float* __restrict__ x,
    const float* __restrict__ noise,
    const float* __restrict__ b2,       // (4,)
    const float4* __restrict__ pacc,
    const int* __restrict__ pdeg,
    float* __restrict__ out,
    float* __restrict__ out_scalars)
{
    __shared__ float sRed[4][5];
    int tid  = threadIdx.x;
    int n    = blockIdx.x * 128 + (tid >> 1);
    int half = tid & 1;

    float a0 = 0.f, a1 = 0.f, a2 = 0.f, a3 = 0.f;
    int dp = 0;
    if (n < NN) {
#pragma unroll
        for (int k = 0; k < NSL / 2; ++k) {
            int o = (2 * k + half) * (NT * TSZ) + n;
            float4 q = pacc[o];
            a0 += q.x; a1 += q.y; a2 += q.z; a3 += q.w;
            dp += pdeg[o];
        }
    }
    a0 += __shfl_xor(a0, 1);
    a1 += __shfl_xor(a1, 1);
    a2 += __shfl_xor(a2, 1);
    a3 += __shfl_xor(a3, 1);
    dp += __shfl_xor(dp, 1);

    float avx = 0.f, avy = 0.f, bc = 0.f, deadf = 0.f, consf = 0.f;
    if (n < NN && half == 0) {
        float cell = x[n * 10 + 4];
        float cm = (cell == 1.0f) ? 1.0f : 0.0f;
        float h0 = tanhf(a0 + b2[0]) * cm;
        float h1 = tanhf(a1 + b2[1]) * cm;
        float h2 = tanhf(a2 + b2[2]) * cm;
        float h3 = tanhf(a3 + b2[3]) * cm;

        float px = x[n * 10 + 0], py = x[n * 10 + 1];
        float vx = x[n * 10 + 2], vy = x[n * 10 + 3];

        float nvx = fminf(fmaxf(fmaf(h0, ACC_SCALE, vx), -MAX_VEL), MAX_VEL);
        float nvy = fminf(fmaxf(fmaf(h1, ACC_SCALE, vy), -MAX_VEL), MAX_VEL);
        float npx = px + nvx;
        float npy = py + nvy;

        float vnx = nvx + (noise[n * 2 + 0] * 2.0f - 1.0f) * NOISE_SCALE * cm;
        float vny = nvy + (noise[n * 2 + 1] * 2.0f - 1.0f) * NOISE_SCALE * cm;

        float* row = out + (size_t)n * 10;
        row[0] = npx;  row[1] = npy;
        row[2] = vnx;  row[3] = vny;
        row[4] = cell; row[5] = h2;  row[6] = h3;
        row[7] = x[n * 10 + 7];
        row[8] = x[n * 10 + 8];
        row[9] = x[n * 10 + 9];

        float apx = fabsf(npx), apy = fabsf(npy);
        if (apx > 1.0f) bc += logf(apx + 1e-6f);
        if (apy > 1.0f) bc += logf(apy + 1e-6f);

        int deg  = dp & 0xFFFF;
        int cdeg = dp >> 16;
        bool dead = (cell == 1.0f) && (deg < 3);
        bool cons = (cell == 0.0f) && (cdeg >= 3);
        out[OUT_KEEP + n] = (dead || cons) ? 0.0f : 1.0f;
        deadf = dead ? 1.0f : 0.0f;
        consf = cons ? 1.0f : 0.0f;
        avx = fabsf(nvx) * (1.0f / NN);
        avy = fabsf(nvy) * (1.0f / NN);
    }

    float r[5] = { avx, avy, bc, consf, deadf };
#pragma unroll
    for (int q = 0; q < 5; ++q) {
#pragma unroll
        for (int off = 32; off > 0; off >>= 1)
            r[q] += __shfl_down(r[q], off);
    }
    int lane = tid & 63, wv = tid >> 6;
    if (lane == 0) {
#pragma unroll
        for (int q = 0; q < 5; ++q) sRed[wv][q] = r[q];
    }
    __syncthreads();
    if (tid == 0) {
#pragma unroll
        for (int q = 0; q < 5; ++q) {
            float acc = sRed[0][q] + sRed[1][q] + sRed[2][q] + sRed[3][q];
            atomicAdd(&out_scalars[q], acc);
        }
    }
}

extern "C" void kernel_launch(void* const* d_in, const int* in_sizes, int n_in,
                              void* d_out, int out_size, void* d_ws, size_t ws_size,
                              hipStream_t stream) {
    const float* x      = (const float*)d_in[0];
    const int*   src    = (const int*)  d_in[1];
    const int*   dst    = (const int*)  d_in[2];
    const float* noise  = (const float*)d_in[3];
    const float* W_edge = (const float*)d_in[4];
    const float* W_src  = (const float*)d_in[5];
    const float* b1     = (const float*)d_in[6];
    const float* W_out  = (const float*)d_in[7];
    const float* b2     = (const float*)d_in[8];

    float* ws = (float*)d_ws;
    float4*   srec   = (float4*)(ws + WS_SREC);
    int*      gcur   = (int*)(ws + WS_GCUR);
    unsigned* bucket = (unsigned*)(ws + WS_BK);
    float4*   pacc   = (float4*)(ws + WS_PACC);
    int*      pdeg   = (int*)(ws + WS_PDEG);

    float* out         = (float*)d_out;
    float* out_scalars = out + OUT_SCAL;

    k1_prep<<<196, 256, 0, stream>>>(
        x, W_edge, W_src, b1, srec, gcur, out_scalars);

    k_scatter<<<SCB, 256, 0, stream>>>(src, dst, gcur, bucket);

    k_agg<<<NT * NSL, 256, 0, stream>>>(
        W_edge, W_out, srec, gcur, bucket, pacc, pdeg, out_scalars);

    k_final<<<392, 256, 0, stream>>>(
        x, noise, b2, pacc, pdeg, out, out_scalars);
}